// Round 2
// baseline (888.210 us; speedup 1.0000x reference)
//
#include <hip/hip_runtime.h>

#define NN 50000
#define NE 800000
#define D 64

typedef float v4f __attribute__((ext_vector_type(4)));
typedef int v2i __attribute__((ext_vector_type(2)));

__global__ __launch_bounds__(256) void edge_kernel(
    const float* __restrict__ feats, const int* __restrict__ ei,
    const float* __restrict__ ea, const float* __restrict__ W1,
    const float* __restrict__ b1, const float* __restrict__ W2,
    const float* __restrict__ b2, float* __restrict__ e_out,
    float* __restrict__ agg, float* __restrict__ deg) {
    __shared__ float tbuf[4][64 * 17];  // wave-private transpose tile
    __shared__ int cbuf[4][64];         // dest node per edge
    const int tid = threadIdx.x;
    const int w = tid >> 6;
    const int lane = tid & 63;
    const int eid = blockIdx.x * 256 + tid;       // grid*block == NE exactly
    const int ebase = blockIdx.x * 256 + w * 64;  // first edge of this wave

    const v2i rc = __builtin_nontemporal_load((const v2i*)ei + eid);
    const int r = rc[0];
    const int c = rc[1];
    cbuf[w][lane] = c;

    float h[D];
    #pragma unroll
    for (int j = 0; j < D; ++j) h[j] = b1[j];

    const v4f* s0 = (const v4f*)(feats + (size_t)r * D);
    const v4f* s1 = (const v4f*)(feats + (size_t)c * D);
    const v4f* s2 = (const v4f*)(ea + (size_t)eid * D);

    // ---- layer 1: flat 24-chunk loop, software-prefetched one chunk ahead.
    // Chunk cc covers W1 rows [cc*8, cc*8+8); segments: 0-7 feats[r],
    // 8-15 feats[c], 16-23 edge_attr (nontemporal: stream-once).
    v4f c0v = s0[0], c1v = s0[1];
    #pragma unroll 1
    for (int cc = 0; cc < 24; ++cc) {
        const int nc = cc + 1;
        const v4f* nb = (nc < 8) ? s0 : ((nc < 16) ? s1 : s2);
        const int off = (nc & 7) * 2;
        v4f n0, n1;
        if (nc >= 16) {  // uniform branch (loop counter)
            n0 = __builtin_nontemporal_load(nb + off);
            n1 = __builtin_nontemporal_load(nb + off + 1);
        } else {
            n0 = nb[off];
            n1 = nb[off + 1];
        }
        float xa[8] = {c0v[0], c0v[1], c0v[2], c0v[3],
                       c1v[0], c1v[1], c1v[2], c1v[3]};
        const float* Wr = W1 + cc * 8 * D;
        #pragma unroll
        for (int kk = 0; kk < 8; ++kk) {
            const float xk = xa[kk];
            #pragma unroll
            for (int j = 0; j < D; ++j) h[j] = fmaf(xk, Wr[kk * D + j], h[j]);
        }
        c0v = n0;
        c1v = n1;
    }

    // ReLU in place; h[64] is the only big live set from here on.
    #pragma unroll
    for (int k = 0; k < D; ++k) h[k] = fmaxf(h[k], 0.f);

    // ---- layer 2 (k-outer per 16-col block; W2 rows via s_load_dwordx16)
    // fused with transposed, line-coalesced emission.
    float* T = tbuf[w];
    const int es = lane >> 4;  // edge subgroup 0..3 (atomic phase)
    const int js = lane & 15;  // column within 16-wide chunk
    const int e4 = lane >> 2;  // edge-in-16 (store phase)
    const int qd = lane & 3;   // j-quad (store phase)
    #pragma unroll 1
    for (int c0 = 0; c0 < D; c0 += 16) {
        float acc[16];
        #pragma unroll
        for (int j = 0; j < 16; ++j) acc[j] = b2[c0 + j];
        #pragma unroll
        for (int k = 0; k < D; ++k) {
            const float hk = h[k];
            const float* Wr = W2 + k * D + c0;  // uniform 64B row segment
            #pragma unroll
            for (int j = 0; j < 16; ++j) acc[j] = fmaf(hk, Wr[j], acc[j]);
        }
        #pragma unroll
        for (int i = 0; i < 16; ++i) T[lane * 17 + i] = acc[i];
        // e_out: x4 stores — 16 lanes x 16B = 16 full rows' quads per instr.
        #pragma unroll 1
        for (int g2 = 0; g2 < 4; ++g2) {
            const int o = g2 * 16 + e4;
            v4f v;
            #pragma unroll
            for (int i = 0; i < 4; ++i) v[i] = T[o * 17 + qd * 4 + i];
            __builtin_nontemporal_store(
                v, (v4f*)(e_out + (size_t)(ebase + o) * D + c0 + qd * 4));
        }
        // agg atomics: 4 full 64B lines per instruction.
        #pragma unroll 1
        for (int g = 0; g < 16; ++g) {
            const int o = g * 4 + es;
            const float v = T[o * 17 + js];
            const int cd = cbuf[w][o];  // broadcast read
            unsafeAtomicAdd(agg + (size_t)cd * D + c0 + js, v);
        }
    }
    unsafeAtomicAdd(deg + c, 1.0f);
}

// 4 threads per node: thread quarter q computes h[q*16..q*16+16) and then
// out[:, q*16..q*16+16). h exchanged via stride-65 LDS (conflict-free).
__global__ __launch_bounds__(256) void node_kernel(
    const float* __restrict__ feats, const float* __restrict__ agg,
    const float* __restrict__ deg, const float* __restrict__ W1,
    const float* __restrict__ b1, const float* __restrict__ W2,
    const float* __restrict__ b2, float* __restrict__ out) {
    __shared__ float sh[64 * 65];  // 16640 B
    const int tid = threadIdx.x;
    const int lane = tid & 63;  // node within block
    const int q = tid >> 6;     // output quarter
    int n = blockIdx.x * 64 + lane;
    const bool valid = (n < NN);
    if (!valid) n = NN - 1;  // clamp for safe loads; store is guarded

    const float rd = 1.0f / fmaxf(deg[n], 1.0f);

    float h16[16];
    #pragma unroll
    for (int j = 0; j < 16; ++j) h16[j] = b1[q * 16 + j];

    const v4f* s0 = (const v4f*)(feats + (size_t)n * D);
    const v4f* s1 = (const v4f*)(agg + (size_t)n * D);

    // 16-chunk prefetched loop: rows 0-63 feats, 64-127 agg (scaled by rd).
    v4f c0v = s0[0], c1v = s0[1];
    #pragma unroll 1
    for (int cc = 0; cc < 16; ++cc) {
        const int nc = cc + 1;
        const v4f* nb = (nc < 8) ? s0 : s1;
        const int off = (nc & 7) * 2;
        v4f n0 = nb[off], n1 = nb[off + 1];
        const float sc = (cc < 8) ? 1.0f : rd;
        float xa[8] = {c0v[0], c0v[1], c0v[2], c0v[3],
                       c1v[0], c1v[1], c1v[2], c1v[3]};
        const float* Wr = W1 + cc * 8 * D + q * 16;
        #pragma unroll
        for (int kk = 0; kk < 8; ++kk) {
            const float xk = xa[kk] * sc;
            #pragma unroll
            for (int j = 0; j < 16; ++j)
                h16[j] = fmaf(xk, Wr[kk * D + j], h16[j]);
        }
        c0v = n0;
        c1v = n1;
    }

    #pragma unroll
    for (int j = 0; j < 16; ++j)
        sh[lane * 65 + q * 16 + j] = fmaxf(h16[j], 0.f);
    __syncthreads();

    float acc[16];
    #pragma unroll
    for (int j = 0; j < 16; ++j) acc[j] = b2[q * 16 + j];
    #pragma unroll
    for (int k = 0; k < D; ++k) {
        const float hk = sh[lane * 65 + k];  // banks (lane+k)%32: conflict-free
        const float* Wr = W2 + k * D + q * 16;
        #pragma unroll
        for (int j = 0; j < 16; ++j) acc[j] = fmaf(hk, Wr[j], acc[j]);
    }

    if (valid) {
        v4f* o4 = (v4f*)(out + (size_t)n * D + q * 16);
        #pragma unroll
        for (int qq = 0; qq < 4; ++qq) {
            v4f v = {acc[4 * qq + 0], acc[4 * qq + 1],
                     acc[4 * qq + 2], acc[4 * qq + 3]};
            o4[qq] = v;
        }
    }
}

extern "C" void kernel_launch(void* const* d_in, const int* in_sizes, int n_in,
                              void* d_out, int out_size, void* d_ws,
                              size_t ws_size, hipStream_t stream) {
    const float* feats = (const float*)d_in[0];
    const int* ei      = (const int*)d_in[1];
    const float* ea    = (const float*)d_in[2];
    const float* W1e   = (const float*)d_in[3];
    const float* b1e   = (const float*)d_in[4];
    const float* W2e   = (const float*)d_in[5];
    const float* b2e   = (const float*)d_in[6];
    const float* W1n   = (const float*)d_in[7];
    const float* b1n   = (const float*)d_in[8];
    const float* W2n   = (const float*)d_in[9];
    const float* b2n   = (const float*)d_in[10];

    float* out_f = (float*)d_out;
    float* feats_out = out_f;                  // NN*D
    float* e_out = out_f + (size_t)NN * D;     // NE*D

    float* agg = (float*)d_ws;                 // NN*D
    float* deg = agg + (size_t)NN * D;         // NN

    hipMemsetAsync(d_ws, 0, ((size_t)NN * D + NN) * sizeof(float), stream);

    edge_kernel<<<NE / 256, 256, 0, stream>>>(feats, ei, ea, W1e, b1e, W2e,
                                              b2e, e_out, agg, deg);
    node_kernel<<<(NN + 63) / 64, 256, 0, stream>>>(feats, agg, deg, W1n, b1n,
                                                    W2n, b2n, feats_out);
}